// Round 3
// baseline (379.110 us; speedup 1.0000x reference)
//
#include <hip/hip_runtime.h>
#include <hip/hip_bf16.h>

typedef __attribute__((ext_vector_type(8))) short short8v;
typedef __attribute__((ext_vector_type(4))) float f32x4;

#define H_  128
#define W_  128
#define C_  256
#define HW_ 16384

#define MFMA32(a, b, c) __builtin_amdgcn_mfma_f32_16x16x32_bf16(a, b, c, 0, 0, 0)

__device__ __forceinline__ short bf16b(float f) {
    unsigned u = __float_as_uint(f);
    u += 0x7fffu + ((u >> 16) & 1u);   // round-to-nearest-even
    return (short)(u >> 16);
}

// 512 threads = 8 waves. Tile: 16h x 16w pixels, all 81 displacements.
// Wave w owns out rows {2w, 2w+1}. K pipelined in 32-channel chunks, ping-pong LDS.
// LDS in2 buf: [r 0..23][j 0..3][col 0..31][8 bf16]; cols 24..31 stay zero.
__global__ __launch_bounds__(512, 1)
void corr_kernel(const float* __restrict__ in1, const float* __restrict__ in2,
                 float* __restrict__ out)
{
    __shared__ short lds2[2][24 * 4 * 32 * 8];   // 2 x 48 KiB ping-pong
    __shared__ float ldso[9 * 257];              // epilogue band->coalesced staging

    const int tid  = threadIdx.x;
    const int lane = tid & 63;
    const int wid  = tid >> 6;        // 0..7
    const int m    = lane & 15;       // M row / N col in 16x16 tile
    const int g    = lane >> 4;       // k-octet 0..3 (8 k's each, K=32)

    int bid = blockIdx.x;
    int swz = (bid & 7) * 64 + (bid >> 3);       // bijective XCD swizzle (512 % 8 == 0)
    int n   = swz >> 6;
    int h0  = ((swz >> 3) & 7) << 4;
    int w0  = (swz & 7) << 4;

    const float* in1n = in1 + (size_t)n * (C_ * HW_);
    const float* in2n = in2 + (size_t)n * (C_ * HW_);

    // ---- chunk-invariant stage geometry: unit u = (r*4+j)*24 + c, 2304 units ----
    int  lwoff[5]; long gbase[5]; bool act[5], inb[5];
#pragma unroll
    for (int s = 0; s < 5; ++s) {
        int u  = tid + s * 512;
        act[s] = (u < 2304);
        int c  = u % 24;
        int rj = u / 24;              // 0..95
        int j  = rj & 3;
        int r  = rj >> 2;
        int row = h0 - 4 + r;
        int col = w0 - 4 + c;
        inb[s] = act[s] && ((unsigned)row < 128u) && ((unsigned)col < 128u);
        gbase[s] = inb[s] ? ((long)(j * 8) * HW_ + (long)row * W_ + col) : 0;
        lwoff[s] = ((r * 4 + j) * 32 + c) * 8;
    }
    const long abase = (long)(8 * g) * HW_ + (long)(h0 + 2 * wid) * W_ + (w0 + m);

    // ---- zero both LDS buffers (cols 24..31 must read as 0), matched store type ----
    {
        short8v z = (short8v)0;
        short8v* zp = (short8v*)&lds2[0][0];
#pragma unroll
        for (int i = 0; i < 12; ++i) zp[tid + i * 512] = z;
    }
    __syncthreads();
    __builtin_amdgcn_sched_barrier(0);

    f32x4 acc[2][9][2];
#pragma unroll
    for (int a = 0; a < 2; ++a)
#pragma unroll
        for (int d = 0; d < 9; ++d)
#pragma unroll
            for (int t = 0; t < 2; ++t)
                acc[a][d][t] = (f32x4){0.f, 0.f, 0.f, 0.f};

    // ---- prologue: stage chunk 0 into buf 0 ----
    {
        float sf[5][8];
#pragma unroll
        for (int s = 0; s < 5; ++s)
            if (act[s])
#pragma unroll
                for (int i = 0; i < 8; ++i) {
                    float v = in2n[gbase[s] + (long)i * HW_];
                    sf[s][i] = inb[s] ? v : 0.f;
                }
#pragma unroll
        for (int s = 0; s < 5; ++s)
            if (act[s]) {
                short8v v8;
#pragma unroll
                for (int i = 0; i < 8; ++i) v8[i] = bf16b(sf[s][i]);
                *(short8v*)&lds2[0][lwoff[s]] = v8;
            }
    }

    // ---- main loop: 8 chunks of 32 channels, ping-pong; stage t+1 overlaps MFMA t ----
#pragma unroll 1
    for (int t = 0; t < 8; ++t) {
        __syncthreads();
        __builtin_amdgcn_sched_barrier(0);
        const int rb = t & 1;

        // A-frags for chunk t (read-once, 64B-coalesced): channel 32t + 8g + i
        float af[2][8];
#pragma unroll
        for (int rs = 0; rs < 2; ++rs)
#pragma unroll
            for (int i = 0; i < 8; ++i)
                af[rs][i] = in1n[abase + (long)(32 * t + i) * HW_ + rs * W_];

        // stage loads for chunk t+1 (issue before MFMA; overlap)
        float sf[5][8];
        if (t < 7) {
            const long koff = (long)((t + 1) * 32) * HW_;
#pragma unroll
            for (int s = 0; s < 5; ++s)
                if (act[s])
#pragma unroll
                    for (int i = 0; i < 8; ++i) {
                        float v = in2n[gbase[s] + koff + (long)i * HW_];
                        sf[s][i] = inb[s] ? v : 0.f;
                    }
        }

        short8v a8[2];
#pragma unroll
        for (int rs = 0; rs < 2; ++rs)
#pragma unroll
            for (int i = 0; i < 8; ++i) a8[rs][i] = bf16b(af[rs][i]);

        // MFMA from buf rb: lane (m,g) reads B[8g+i][ncol] at unit (r, j=g, col=ncol)
        const short* lb = &lds2[rb][0];
#pragma unroll
        for (int dy = 0; dy < 9; ++dy) {
#pragma unroll
            for (int rs = 0; rs < 2; ++rs) {
                int r = 2 * wid + rs + dy;
                int ro = (r * 4 + g) * 256;          // *32 cols *8 k
#pragma unroll
                for (int nt = 0; nt < 2; ++nt) {
                    short8v b = *(const short8v*)&lb[ro + (nt * 16 + m) * 8];
                    acc[rs][dy][nt] = MFMA32(a8[rs], b, acc[rs][dy][nt]);
                }
            }
        }

        // write staged chunk t+1 into the other buffer
        if (t < 7) {
#pragma unroll
            for (int s = 0; s < 5; ++s)
                if (act[s]) {
                    short8v v8;
#pragma unroll
                    for (int i = 0; i < 8; ++i) v8[i] = bf16b(sf[s][i]);
                    *(short8v*)&lds2[rb ^ 1][lwoff[s]] = v8;
                }
        }
    }

    // ---- epilogue: band -> ldso (stride 257) -> coalesced 64B stores ----
    const size_t outb = (size_t)n * 81 * HW_;
#pragma unroll 1
    for (int dy = 0; dy < 9; ++dy) {
        __syncthreads();
        __builtin_amdgcn_sched_barrier(0);
#pragma unroll
        for (int rs = 0; rs < 2; ++rs) {
            int hl = 2 * wid + rs;
#pragma unroll
            for (int nt = 0; nt < 2; ++nt) {
#pragma unroll
                for (int i = 0; i < 4; ++i) {
                    int mm = 4 * g + i;              // D row = pixel w offset
                    int dx = nt * 16 + m - mm;       // D col = mm + dx
                    if (dx >= 0 && dx < 9)
                        ldso[dx * 257 + hl * 16 + mm] = acc[rs][dy][nt][i];
                }
            }
        }
        __syncthreads();
        __builtin_amdgcn_sched_barrier(0);
        for (int t = tid; t < 2304; t += 512) {
            int dx  = t >> 8;
            int rem = t & 255;                       // hl*16 + w
            out[outb + (size_t)(dy * 9 + dx) * HW_ +
                (size_t)(h0 + (rem >> 4)) * W_ + (w0 + (rem & 15))] = ldso[dx * 257 + rem];
        }
    }
}

extern "C" void kernel_launch(void* const* d_in, const int* in_sizes, int n_in,
                              void* d_out, int out_size, void* d_ws, size_t ws_size,
                              hipStream_t stream) {
    const float* in1 = (const float*)d_in[0];
    const float* in2 = (const float*)d_in[1];
    float* out = (float*)d_out;
    corr_kernel<<<dim3(512), dim3(512), 0, stream>>>(in1, in2, out);
}

// Round 4
// 106.180 us; speedup vs baseline: 3.5705x; 3.5705x over previous
//
#include <hip/hip_runtime.h>
#include <hip/hip_bf16.h>

typedef __attribute__((ext_vector_type(8))) short short8v;
typedef __attribute__((ext_vector_type(4))) float f32x4;

#define H_  128
#define W_  128
#define C_  256
#define HW_ 16384

#define MFMA32(a, b, c) __builtin_amdgcn_mfma_f32_16x16x32_bf16(a, b, c, 0, 0, 0)

__device__ __forceinline__ short bf16b(float f) {
    unsigned u = __float_as_uint(f);
    u += 0x7fffu + ((u >> 16) & 1u);   // round-to-nearest-even
    return (short)(u >> 16);
}

// 512 threads = 8 waves. Tile: 16h x 16w pixels, all 81 displacements.
// Wave w owns out rows {2w, 2w+1}. K pipelined in 32-channel chunks, ping-pong LDS.
// LDS in2 buf: [r 0..23][j 0..3][col 0..31][8 bf16]; cols 24..31 stay zero.
// NOTE: every index into acc[][][] must be compile-time constant (full unroll) —
// a single runtime index demotes the whole array to scratch (round-3: 120 VGPR,
// 1.37 GB spill writes, 379us).
__global__ __launch_bounds__(512, 2)
void corr_kernel(const float* __restrict__ in1, const float* __restrict__ in2,
                 float* __restrict__ out)
{
    __shared__ short lds2[2][24 * 4 * 32 * 8];   // 2 x 48 KiB ping-pong
    __shared__ float ldso[9 * 257];              // epilogue band->coalesced staging

    const int tid  = threadIdx.x;
    const int lane = tid & 63;
    const int wid  = tid >> 6;        // 0..7
    const int m    = lane & 15;       // M row / N col in 16x16 tile
    const int g    = lane >> 4;       // k-octet 0..3 (8 k's each, K=32)

    int bid = blockIdx.x;
    int swz = (bid & 7) * 64 + (bid >> 3);       // bijective XCD swizzle (512 % 8 == 0)
    int n   = swz >> 6;
    int h0  = ((swz >> 3) & 7) << 4;
    int w0  = (swz & 7) << 4;

    const float* in1n = in1 + (size_t)n * (C_ * HW_);
    const float* in2n = in2 + (size_t)n * (C_ * HW_);

    // ---- chunk-invariant stage geometry: unit u = (r*4+j)*24 + c, 2304 units ----
    int  lwoff[5]; long gbase[5]; bool act[5], inb[5];
#pragma unroll
    for (int s = 0; s < 5; ++s) {
        int u  = tid + s * 512;
        act[s] = (u < 2304);
        int c  = u % 24;
        int rj = u / 24;              // 0..95
        int j  = rj & 3;
        int r  = rj >> 2;
        int row = h0 - 4 + r;
        int col = w0 - 4 + c;
        inb[s] = act[s] && ((unsigned)row < 128u) && ((unsigned)col < 128u);
        gbase[s] = inb[s] ? ((long)(j * 8) * HW_ + (long)row * W_ + col) : 0;
        lwoff[s] = ((r * 4 + j) * 32 + c) * 8;
    }
    const long abase = (long)(8 * g) * HW_ + (long)(h0 + 2 * wid) * W_ + (w0 + m);

    // ---- zero both LDS buffers (cols 24..31 must read as 0), matched store type ----
    {
        short8v z = (short8v)0;
        short8v* zp = (short8v*)&lds2[0][0];
#pragma unroll
        for (int i = 0; i < 12; ++i) zp[tid + i * 512] = z;
    }
    __syncthreads();
    __builtin_amdgcn_sched_barrier(0);

    f32x4 acc[2][9][2];
#pragma unroll
    for (int a = 0; a < 2; ++a)
#pragma unroll
        for (int d = 0; d < 9; ++d)
#pragma unroll
            for (int t = 0; t < 2; ++t)
                acc[a][d][t] = (f32x4){0.f, 0.f, 0.f, 0.f};

    // ---- prologue: stage chunk 0 into buf 0 ----
    {
        float sf[5][8];
#pragma unroll
        for (int s = 0; s < 5; ++s)
            if (act[s])
#pragma unroll
                for (int i = 0; i < 8; ++i) {
                    float v = in2n[gbase[s] + (long)i * HW_];
                    sf[s][i] = inb[s] ? v : 0.f;
                }
#pragma unroll
        for (int s = 0; s < 5; ++s)
            if (act[s]) {
                short8v v8;
#pragma unroll
                for (int i = 0; i < 8; ++i) v8[i] = bf16b(sf[s][i]);
                *(short8v*)&lds2[0][lwoff[s]] = v8;
            }
    }

    // ---- main loop: 8 chunks of 32 channels, ping-pong; stage t+1 overlaps MFMA t ----
#pragma unroll 1
    for (int t = 0; t < 8; ++t) {
        __syncthreads();
        __builtin_amdgcn_sched_barrier(0);
        const int rb = t & 1;

        // A-frags for chunk t (read-once, 64B-coalesced): channel 32t + 8g + i
        float af[2][8];
#pragma unroll
        for (int rs = 0; rs < 2; ++rs)
#pragma unroll
            for (int i = 0; i < 8; ++i)
                af[rs][i] = in1n[abase + (long)(32 * t + i) * HW_ + rs * W_];

        // stage loads for chunk t+1 (issue before MFMA; overlap)
        float sf[5][8];
        if (t < 7) {
            const long koff = (long)((t + 1) * 32) * HW_;
#pragma unroll
            for (int s = 0; s < 5; ++s)
                if (act[s])
#pragma unroll
                    for (int i = 0; i < 8; ++i) {
                        float v = in2n[gbase[s] + koff + (long)i * HW_];
                        sf[s][i] = inb[s] ? v : 0.f;
                    }
        }

        short8v a8[2];
#pragma unroll
        for (int rs = 0; rs < 2; ++rs)
#pragma unroll
            for (int i = 0; i < 8; ++i) a8[rs][i] = bf16b(af[rs][i]);

        // MFMA from buf rb: lane (m,g) reads B[8g+i][ncol] at unit (r, j=g, col=ncol)
        const short* lb = &lds2[rb][0];
#pragma unroll
        for (int dy = 0; dy < 9; ++dy) {
#pragma unroll
            for (int rs = 0; rs < 2; ++rs) {
                int r = 2 * wid + rs + dy;
                int ro = (r * 4 + g) * 256;          // *32 cols *8 k
#pragma unroll
                for (int nt = 0; nt < 2; ++nt) {
                    short8v b = *(const short8v*)&lb[ro + (nt * 16 + m) * 8];
                    acc[rs][dy][nt] = MFMA32(a8[rs], b, acc[rs][dy][nt]);
                }
            }
        }

        // write staged chunk t+1 into the other buffer
        if (t < 7) {
#pragma unroll
            for (int s = 0; s < 5; ++s)
                if (act[s]) {
                    short8v v8;
#pragma unroll
                    for (int i = 0; i < 8; ++i) v8[i] = bf16b(sf[s][i]);
                    *(short8v*)&lds2[rb ^ 1][lwoff[s]] = v8;
                }
        }
    }

    // ---- epilogue: band -> ldso (stride 257) -> coalesced 64B stores ----
    // FULLY unrolled over dy: acc indices must stay compile-time constants.
    const size_t outb = (size_t)n * 81 * HW_;
#pragma unroll
    for (int dy = 0; dy < 9; ++dy) {
        __syncthreads();
        __builtin_amdgcn_sched_barrier(0);
#pragma unroll
        for (int rs = 0; rs < 2; ++rs) {
            int hl = 2 * wid + rs;
#pragma unroll
            for (int nt = 0; nt < 2; ++nt) {
#pragma unroll
                for (int i = 0; i < 4; ++i) {
                    int mm = 4 * g + i;              // D row = pixel w offset
                    int dx = nt * 16 + m - mm;       // D col = mm + dx
                    if (dx >= 0 && dx < 9)
                        ldso[dx * 257 + hl * 16 + mm] = acc[rs][dy][nt][i];
                }
            }
        }
        __syncthreads();
        __builtin_amdgcn_sched_barrier(0);
#pragma unroll
        for (int e = 0; e < 5; ++e) {
            int t = tid + e * 512;
            if (t < 2304) {
                int dx  = t >> 8;
                int rem = t & 255;                   // hl*16 + w
                out[outb + (size_t)(dy * 9 + dx) * HW_ +
                    (size_t)(h0 + (rem >> 4)) * W_ + (w0 + (rem & 15))] = ldso[dx * 257 + rem];
            }
        }
    }
}

extern "C" void kernel_launch(void* const* d_in, const int* in_sizes, int n_in,
                              void* d_out, int out_size, void* d_ws, size_t ws_size,
                              hipStream_t stream) {
    const float* in1 = (const float*)d_in[0];
    const float* in2 = (const float*)d_in[1];
    float* out = (float*)d_out;
    corr_kernel<<<dim3(512), dim3(512), 0, stream>>>(in1, in2, out);
}